// Round 5
// baseline (292.670 us; speedup 1.0000x reference)
//
#include <hip/hip_runtime.h>
#include <math.h>

// MoE Router V6: x(16384,2048) fp32, W(128,2048) fp32, bias(128) fp32
// out = [weights(16384,8) fp32 | indices(16384,8) as fp32]
//
// R8: TOKT 64 -> 32. R7 post-mortem: grid was 256 blocks = exactly 1
//  block/CU (occupancy pinned at 22% = 8 waves/CU); the per-chunk
//  barrier+lgkmcnt chain was fully exposed with only 2 waves/SIMD.
//  Grid 512 = 2 independent blocks/CU (independent barrier sets overlap),
//  and per-wave chunk work halves (12 MFMA, 3 ds_read, 6 W loads).
//  Bit-exact with passing R6/R7: same fragment values, same 6-MFMA
//  chunk-order chain per accumulator, same slice grouping/combine, same
//  topk. Only wave<->token assignment changes.
//  Structure: W planes global->VGPR double-buffered (wp L2-resident);
//  x -> LDS (stride-40 rows); raw s_barrier + lgkmcnt(0) only; logits L
//  aliases the staging arena. LDS 16.6 KB.

#define NE      128
#define TOKT    32
#define KC      32
#define DMODEL  2048
#define NT      (DMODEL / KC)        // 64 k-chunks
#define CHUNK_SH (3 * NE * KC)       // 12288 shorts per chunk image
#define XPAD    40                   // xsm row stride in shorts (80 B)

typedef __attribute__((ext_vector_type(8))) short short8;
typedef __attribute__((ext_vector_type(4))) short s16x4;
typedef __attribute__((ext_vector_type(4))) float f32x4;
typedef __attribute__((ext_vector_type(2))) float f32x2;

union S4u { short s[4]; s16x4 v; };

// split one fp32 into 3 truncated bf16 planes (exact residuals)
__device__ __forceinline__ void split3(float f, S4u& hi, S4u& mi, S4u& lo, int j) {
  const unsigned u0 = __float_as_uint(f);
  const float hif = __uint_as_float(u0 & 0xFFFF0000u);
  const float r1 = f - hif;                      // exact
  const unsigned u1 = __float_as_uint(r1);
  const float mif = __uint_as_float(u1 & 0xFFFF0000u);
  const float r2 = r1 - mif;                     // exact
  hi.s[j] = (short)(u0 >> 16);
  mi.s[j] = (short)(u1 >> 16);
  lo.s[j] = (short)(__float_as_uint(r2) >> 16);
}

// W planes precompute: wp[chunk][p][e][kk], identical split3 as x path.
__global__ __launch_bounds__(256) void wprep(const float* __restrict__ w,
                                             short* __restrict__ wp) {
  const int gid = blockIdx.x * 256 + threadIdx.x;  // 65536 threads
  const int e = gid >> 9;                          // expert 0..127
  const int g = gid & 511;                         // float4 group in row
  const int k = g << 2;
  const int chunk = k >> 5;
  const int kk = k & 31;
  const f32x4 a = *(const f32x4*)(w + (size_t)e * DMODEL + k);
  S4u hi, mi, lo;
  split3(a[0], hi, mi, lo, 0); split3(a[1], hi, mi, lo, 1);
  split3(a[2], hi, mi, lo, 2); split3(a[3], hi, mi, lo, 3);
  short* base = wp + (size_t)chunk * CHUNK_SH + (size_t)e * KC + kk;
  *(s16x4*)(base)               = hi.v;
  *(s16x4*)(base + NE * KC)     = mi.v;
  *(s16x4*)(base + 2 * NE * KC) = lo.v;
}

__global__ __launch_bounds__(512, 4) void router_fused(
    const float* __restrict__ x, const short* __restrict__ wp,
    const float* __restrict__ bias, float* __restrict__ outW,
    float* __restrict__ outI, int N) {
  // arena: xsm[2][3][32][XPAD] shorts (15360 B) during K-loop,
  //        L[32][130] floats (16640 B) afterwards.
  __shared__ __align__(16) char arena[TOKT * (NE + 2) * 4];
  typedef short XsmT[3][TOKT][XPAD];
  XsmT* xsm = (XsmT*)arena;                       // xsm[buf][p][row][k]
  float (*L)[NE + 2] = (float (*)[NE + 2])arena;  // stride 130 floats

  const int tid  = threadIdx.x;
  const int wv   = tid >> 6;        // 0..7
  const int lane = tid & 63;
  const int wm   = wv >> 2;         // token half of 32 (0..1 -> rows 0-15/16-31)
  const int wn   = wv & 3;          // expert quarter (0..3)
  const int quad = lane >> 4;
  const int l16  = lane & 15;
  const size_t tokBase = (size_t)blockIdx.x * TOKT;

  // x staging: thread -> (row r, float2 group kp) of the 32x32 chunk
  const int r  = tid >> 4;          // 0..31
  const int kp = (tid & 15) * 2;    // 0,2,..,30
  const float* xg = x + (tokBase + r) * (size_t)DMODEL + kp;

  // per-lane W fragment base: expert row (wn*32 + nt*16 + l16), cols quad*8..
  const short* wfb = wp + (size_t)(wn * 32 + l16) * KC + quad * 8;

  // 4 slice accumulators (R3/R6 split-K order); ALL indexing compile-time.
  f32x4 accs[4][2];
#pragma unroll
  for (int s = 0; s < 4; ++s)
#pragma unroll
    for (int j = 0; j < 2; ++j) accs[s][j] = (f32x4)(0.f);

  // ---- helpers (buf literal at call sites -> constant-folds) ----
  auto load_bf = [&](short8 (&bf)[2][3], int c) {
    const short* b = wfb + (size_t)c * CHUNK_SH;
#pragma unroll
    for (int nt = 0; nt < 2; ++nt)
#pragma unroll
      for (int p = 0; p < 3; ++p)
        bf[nt][p] = *(const short8*)(b + p * (NE * KC) + nt * 16 * KC);
  };
  auto stage_x = [&](int buf, f32x2 xr) {
    // split 2 floats -> 3 planes, pack each plane's 2 shorts into one int
    S4u hi, mi, lo;
    split3(xr[0], hi, mi, lo, 0); split3(xr[1], hi, mi, lo, 1);
    *(int*)&xsm[buf][0][r][kp] =
        (int)(unsigned short)hi.s[0] | ((int)(unsigned short)hi.s[1] << 16);
    *(int*)&xsm[buf][1][r][kp] =
        (int)(unsigned short)mi.s[0] | ((int)(unsigned short)mi.s[1] << 16);
    *(int*)&xsm[buf][2][r][kp] =
        (int)(unsigned short)lo.s[0] | ((int)(unsigned short)lo.s[1] << 16);
  };
  auto compute = [&](int buf, const short8 (&bf)[2][3], f32x4 (&acc)[2]) {
    short8 af[3];
#pragma unroll
    for (int p = 0; p < 3; ++p)
      af[p] = *(const short8*)&xsm[buf][p][wm * 16 + l16][quad * 8];
#pragma unroll
    for (int nt = 0; nt < 2; ++nt) {
      f32x4 c = acc[nt];
      c = __builtin_amdgcn_mfma_f32_16x16x32_bf16(af[0], bf[nt][0], c, 0, 0, 0); // x1w1
      c = __builtin_amdgcn_mfma_f32_16x16x32_bf16(af[0], bf[nt][1], c, 0, 0, 0); // x1w2
      c = __builtin_amdgcn_mfma_f32_16x16x32_bf16(af[1], bf[nt][0], c, 0, 0, 0); // x2w1
      c = __builtin_amdgcn_mfma_f32_16x16x32_bf16(af[0], bf[nt][2], c, 0, 0, 0); // x1w3
      c = __builtin_amdgcn_mfma_f32_16x16x32_bf16(af[2], bf[nt][0], c, 0, 0, 0); // x3w1
      c = __builtin_amdgcn_mfma_f32_16x16x32_bf16(af[1], bf[nt][1], c, 0, 0, 0); // x2w2
      acc[nt] = c;
    }
  };
  auto lds_barrier = [&]() {
    asm volatile("s_waitcnt lgkmcnt(0)" ::: "memory");
    __builtin_amdgcn_s_barrier();
  };

  // ---- prologue: bfA = W chunk 0; x chunks 0,1 in regs; xsm buf0 = chunk 0
  short8 bfA[2][3], bfB[2][3];
  load_bf(bfA, 0);
  f32x2 xra = *(const f32x2*)(xg);        // x chunk 0
  f32x2 xrb = *(const f32x2*)(xg + KC);   // x chunk 1
  stage_x(0, xra);
  lds_barrier();

  // ---- main K loop: slice loop unrolled (static accs[s]), chunk loop rolled.
#pragma unroll
  for (int s = 0; s < 4; ++s) {
#pragma unroll 1
    for (int u = 0; u < 16; u += 2) {
      const int t = s * 16 + u;
      // even body: compute chunk t (buf0, bfA); prefetch W t+1, x t+2
      if (t + 1 < NT) load_bf(bfB, t + 1);
      if (t + 2 < NT) xra = *(const f32x2*)(xg + (t + 2) * KC);
      compute(0, bfA, accs[s]);
      if (t + 1 < NT) { stage_x(1, xrb); lds_barrier(); }
      // odd body: compute chunk t+1 (buf1, bfB); prefetch W t+2, x t+3
      if (t + 2 < NT) load_bf(bfA, t + 2);
      if (t + 3 < NT) xrb = *(const f32x2*)(xg + (t + 3) * KC);
      if (t + 1 < NT) compute(1, bfB, accs[s]);
      if (t + 2 < NT) { stage_x(0, xra); lds_barrier(); }
    }
  }

  // arena reuse: make sure every wave is done with xsm before L overwrites it
  __syncthreads();

  // ---- combine slices in R3/R6 order (((p0+p1)+p2)+p3) -> logits LDS.
  // C/D layout: col(expert)=l16, row(token)=quad*4+reg  (verified)
#pragma unroll
  for (int nt = 0; nt < 2; ++nt)
#pragma unroll
    for (int reg = 0; reg < 4; ++reg) {
      float v = accs[0][nt][reg];
      v += accs[1][nt][reg];
      v += accs[2][nt][reg];
      v += accs[3][nt][reg];
      L[wm * 16 + quad * 4 + reg][wn * 32 + nt * 16 + l16] = v;
    }
  __syncthreads();

  // ---- softmax + top-8 + L2 normalize (verified wave-per-token code)
  const float bmy0 = bias[lane];
  const float bmy1 = bias[lane + 64];
  for (int i = 0; i < 4; ++i) {
    const int tk = wv * 4 + i;
    const float l0 = L[tk][lane];
    const float l1 = L[tk][lane + 64];

    float m = fmaxf(l0, l1);
#pragma unroll
    for (int off = 1; off < 64; off <<= 1) m = fmaxf(m, __shfl_xor(m, off));
    const float ev0 = __expf(l0 - m);
    const float ev1 = __expf(l1 - m);
    float zs = ev0 + ev1;
#pragma unroll
    for (int off = 1; off < 64; off <<= 1) zs += __shfl_xor(zs, off);
    const float s0 = ev0 / zs;
    const float s1 = ev1 / zs;

    float b0 = s0 + bmy0;
    float b1 = s1 + bmy1;

    float myv = 0.f;
    int myi = 0;
    float ss = 0.f;
#pragma unroll
    for (int rnd = 0; rnd < 8; ++rnd) {
      float key; int idx;
      if (b0 >= b1) { key = b0; idx = lane; }
      else          { key = b1; idx = lane + 64; }
#pragma unroll
      for (int off = 1; off < 64; off <<= 1) {
        const float k2 = __shfl_xor(key, off);
        const int   i2 = __shfl_xor(idx, off);
        if (k2 > key || (k2 == key && i2 < idx)) { key = k2; idx = i2; }
      }
      const float cand = (idx < 64) ? s0 : s1;
      const float sw = __shfl(cand, idx & 63);
      ss = fmaf(sw, sw, ss);
      if (lane == rnd) { myv = sw; myi = idx; }
      if (lane == (idx & 63)) { if (idx < 64) b0 = -INFINITY; else b1 = -INFINITY; }
    }

    const float inv = 1.f / sqrtf(ss);
    if (lane < 8) {
      const size_t tok = tokBase + tk;
      outW[tok * 8 + lane] = myv * inv;
      outI[tok * 8 + lane] = (float)myi;
    }
  }
}

extern "C" void kernel_launch(void* const* d_in, const int* in_sizes, int n_in,
                              void* d_out, int out_size, void* d_ws, size_t ws_size,
                              hipStream_t stream) {
  const float* x    = (const float*)d_in[0];
  const float* w    = (const float*)d_in[1];
  const float* bias = (const float*)d_in[2];
  float* out = (float*)d_out;

  const int N = in_sizes[0] / DMODEL;  // 16384 tokens
  short* wp = (short*)d_ws;            // 64 chunks * 12288 shorts * 2 B = 1.5 MiB

  wprep<<<256, 256, 0, stream>>>(w, wp);
  router_fused<<<N / TOKT, 512, 0, stream>>>(x, wp, bias, out, out + (size_t)N * 8, N);
}

// Round 6
// 260.331 us; speedup vs baseline: 1.1242x; 1.1242x over previous
//
#include <hip/hip_runtime.h>
#include <math.h>

// MoE Router V7: x(16384,2048) fp32, W(128,2048) fp32, bias(128) fp32
// out = [weights(16384,8) fp32 | indices(16384,8) as fp32]
//
// R9: BARRIER-FREE K-loop. R6/R7/R8 post-mortems: any structure with a
//  per-chunk s_barrier is stuck at 135-160us (5900 cyc/chunk wall vs ~600
//  cyc work; occupancy didn't help). The barriers existed only to stage x
//  through LDS. The 16x16x32 A-fragment (lane(l16,quad) holds row l16,
//  k=quad*8..+7) is directly loadable from global x: 8 contiguous floats
//  per lane, split3'd in registers. So: NO LDS, NO barriers in the K-loop;
//  every wave free-runs.
//  Wave specialization keeps R3/R6 bit-exactness: 8 waves = 4 K-slices x
//  2 expert-halves. Each wave: 32 tokens x 64 experts x its 16 chunks
//  (ascending, identical 6-MFMA chain per accumulator), partials to
//  Lp[s][32][130], ONE __syncthreads, reader combines ((p0+p1)+p2)+p3
//  (exact R3 order) then the verified top-8. W streams global->VGPR
//  (wp L2-resident) with a 1-step pipeline; x read 2x (expert halves),
//  L3-served. LDS 65KB (Lp only) -> 2 blocks/CU; VGPR ~110 <= 128 cap.

#define NE      128
#define TOKT    32
#define KC      32
#define DMODEL  2048
#define NT      (DMODEL / KC)        // 64 k-chunks
#define CHUNK_SH (3 * NE * KC)       // 12288 shorts per chunk image

typedef __attribute__((ext_vector_type(8))) short short8;
typedef __attribute__((ext_vector_type(4))) short s16x4;
typedef __attribute__((ext_vector_type(4))) float f32x4;

union S8  { short s[8]; short8 v; };
union S4u { short s[4]; s16x4 v; };

// split one fp32 into 3 truncated bf16 planes (exact residuals), slot j of 8
__device__ __forceinline__ void split3(float f, S8& hi, S8& mi, S8& lo, int j) {
  const unsigned u0 = __float_as_uint(f);
  const float hif = __uint_as_float(u0 & 0xFFFF0000u);
  const float r1 = f - hif;                      // exact
  const unsigned u1 = __float_as_uint(r1);
  const float mif = __uint_as_float(u1 & 0xFFFF0000u);
  const float r2 = r1 - mif;                     // exact
  hi.s[j] = (short)(u0 >> 16);
  mi.s[j] = (short)(u1 >> 16);
  lo.s[j] = (short)(__float_as_uint(r2) >> 16);
}

// 4-slot variant for wprep (kept verbatim from passing kernels)
__device__ __forceinline__ void split3w(float f, S4u& hi, S4u& mi, S4u& lo, int j) {
  const unsigned u0 = __float_as_uint(f);
  const float hif = __uint_as_float(u0 & 0xFFFF0000u);
  const float r1 = f - hif;
  const unsigned u1 = __float_as_uint(r1);
  const float mif = __uint_as_float(u1 & 0xFFFF0000u);
  const float r2 = r1 - mif;
  hi.s[j] = (short)(u0 >> 16);
  mi.s[j] = (short)(u1 >> 16);
  lo.s[j] = (short)(__float_as_uint(r2) >> 16);
}

// W planes precompute: wp[chunk][p][e][kk], identical split3 as x path.
__global__ __launch_bounds__(256) void wprep(const float* __restrict__ w,
                                             short* __restrict__ wp) {
  const int gid = blockIdx.x * 256 + threadIdx.x;  // 65536 threads
  const int e = gid >> 9;                          // expert 0..127
  const int g = gid & 511;                         // float4 group in row
  const int k = g << 2;
  const int chunk = k >> 5;
  const int kk = k & 31;
  const f32x4 a = *(const f32x4*)(w + (size_t)e * DMODEL + k);
  S4u hi, mi, lo;
  split3w(a[0], hi, mi, lo, 0); split3w(a[1], hi, mi, lo, 1);
  split3w(a[2], hi, mi, lo, 2); split3w(a[3], hi, mi, lo, 3);
  short* base = wp + (size_t)chunk * CHUNK_SH + (size_t)e * KC + kk;
  *(s16x4*)(base)               = hi.v;
  *(s16x4*)(base + NE * KC)     = mi.v;
  *(s16x4*)(base + 2 * NE * KC) = lo.v;
}

__global__ __launch_bounds__(512, 4) void router_fused(
    const float* __restrict__ x, const short* __restrict__ wp,
    const float* __restrict__ bias, float* __restrict__ outW,
    float* __restrict__ outI, int N) {
  // per-slice logit partials; +2 pad puts quad rows 8 banks apart
  __shared__ float Lp[4][TOKT][NE + 2];            // 66560 B

  const int tid  = threadIdx.x;
  const int wv   = tid >> 6;        // 0..7
  const int lane = tid & 63;
  const int sl   = wv >> 1;         // K-slice 0..3  (chunks sl*16 .. sl*16+15)
  const int h    = wv & 1;          // expert half (0..1)
  const int quad = lane >> 4;
  const int l16  = lane & 15;
  const size_t tokBase = (size_t)blockIdx.x * TOKT;

  // A-fragment source: row l16 (+ mt*16), k = t*32 + quad*8 .. +7
  const float* xg = x + (tokBase + l16) * (size_t)DMODEL + quad * 8;
  // B-fragment source: expert h*64 + nt*16 + l16, k = quad*8 .. +7
  const short* wfb = wp + (size_t)(h * 64 + l16) * KC + quad * 8;

  f32x4 acc[2][4];
#pragma unroll
  for (int mt = 0; mt < 2; ++mt)
#pragma unroll
    for (int nt = 0; nt < 4; ++nt) acc[mt][nt] = (f32x4)(0.f);

  short8 bfbuf[2][3];               // 1-step W pipeline (static-indexed)
  auto load_bf = [&](int b, int t, int nt) {
    const short* p0 = wfb + (size_t)t * CHUNK_SH + nt * (16 * KC);
#pragma unroll
    for (int p = 0; p < 3; ++p)
      bfbuf[b][p] = *(const short8*)(p0 + p * (NE * KC));
  };

  // ---- barrier-free K loop over this wave's 16 chunks ----
  load_bf(0, sl * 16, 0);
#pragma unroll 1
  for (int u = 0; u < 16; ++u) {
    const int t = sl * 16 + u;
    // load x fragments for both mt (8 contiguous floats each), split in regs
    const float* xp0 = xg + (size_t)t * KC;
    const float* xp1 = xp0 + 16 * (size_t)DMODEL;
    const f32x4 x0a = *(const f32x4*)(xp0);
    const f32x4 x0b = *(const f32x4*)(xp0 + 4);
    const f32x4 x1a = *(const f32x4*)(xp1);
    const f32x4 x1b = *(const f32x4*)(xp1 + 4);
    short8 af[2][3];
    {
      S8 hi, mi, lo;
      split3(x0a[0], hi, mi, lo, 0); split3(x0a[1], hi, mi, lo, 1);
      split3(x0a[2], hi, mi, lo, 2); split3(x0a[3], hi, mi, lo, 3);
      split3(x0b[0], hi, mi, lo, 4); split3(x0b[1], hi, mi, lo, 5);
      split3(x0b[2], hi, mi, lo, 6); split3(x0b[3], hi, mi, lo, 7);
      af[0][0] = hi.v; af[0][1] = mi.v; af[0][2] = lo.v;
    }
    {
      S8 hi, mi, lo;
      split3(x1a[0], hi, mi, lo, 0); split3(x1a[1], hi, mi, lo, 1);
      split3(x1a[2], hi, mi, lo, 2); split3(x1a[3], hi, mi, lo, 3);
      split3(x1b[0], hi, mi, lo, 4); split3(x1b[1], hi, mi, lo, 5);
      split3(x1b[2], hi, mi, lo, 6); split3(x1b[3], hi, mi, lo, 7);
      af[1][0] = hi.v; af[1][1] = mi.v; af[1][2] = lo.v;
    }
    // nt steps, W prefetched one step ahead (buffer index static post-unroll)
#pragma unroll
    for (int nt = 0; nt < 4; ++nt) {
      if (nt < 3)           load_bf((nt + 1) & 1, t, nt + 1);
      else if (u + 1 < 16)  load_bf(0, t + 1, 0);
      const int b = nt & 1;
#pragma unroll
      for (int mt = 0; mt < 2; ++mt) {
        f32x4 c = acc[mt][nt];
        c = __builtin_amdgcn_mfma_f32_16x16x32_bf16(af[mt][0], bfbuf[b][0], c, 0, 0, 0); // x1w1
        c = __builtin_amdgcn_mfma_f32_16x16x32_bf16(af[mt][0], bfbuf[b][1], c, 0, 0, 0); // x1w2
        c = __builtin_amdgcn_mfma_f32_16x16x32_bf16(af[mt][1], bfbuf[b][0], c, 0, 0, 0); // x2w1
        c = __builtin_amdgcn_mfma_f32_16x16x32_bf16(af[mt][0], bfbuf[b][2], c, 0, 0, 0); // x1w3
        c = __builtin_amdgcn_mfma_f32_16x16x32_bf16(af[mt][2], bfbuf[b][0], c, 0, 0, 0); // x3w1
        c = __builtin_amdgcn_mfma_f32_16x16x32_bf16(af[mt][1], bfbuf[b][1], c, 0, 0, 0); // x2w2
        acc[mt][nt] = c;
      }
    }
  }

  // ---- slice partials -> LDS (disjoint regions), single barrier ----
  // C/D layout: col(expert)=l16, row(token)=quad*4+reg  (verified)
#pragma unroll
  for (int mt = 0; mt < 2; ++mt)
#pragma unroll
    for (int nt = 0; nt < 4; ++nt)
#pragma unroll
      for (int reg = 0; reg < 4; ++reg)
        Lp[sl][mt * 16 + quad * 4 + reg][h * 64 + nt * 16 + l16] =
            acc[mt][nt][reg];
  __syncthreads();

  // ---- softmax + top-8 + L2 normalize (verified wave-per-token code);
  //      logits combined in exact R3 order ((p0+p1)+p2)+p3 ----
  const float bmy0 = bias[lane];
  const float bmy1 = bias[lane + 64];
  for (int i = 0; i < 4; ++i) {
    const int tk = wv * 4 + i;
    float l0 = Lp[0][tk][lane];
    l0 += Lp[1][tk][lane];
    l0 += Lp[2][tk][lane];
    l0 += Lp[3][tk][lane];
    float l1 = Lp[0][tk][lane + 64];
    l1 += Lp[1][tk][lane + 64];
    l1 += Lp[2][tk][lane + 64];
    l1 += Lp[3][tk][lane + 64];

    float m = fmaxf(l0, l1);
#pragma unroll
    for (int off = 1; off < 64; off <<= 1) m = fmaxf(m, __shfl_xor(m, off));
    const float ev0 = __expf(l0 - m);
    const float ev1 = __expf(l1 - m);
    float zs = ev0 + ev1;
#pragma unroll
    for (int off = 1; off < 64; off <<= 1) zs += __shfl_xor(zs, off);
    const float s0 = ev0 / zs;
    const float s1 = ev1 / zs;

    float b0 = s0 + bmy0;
    float b1 = s1 + bmy1;

    float myv = 0.f;
    int myi = 0;
    float ss = 0.f;
#pragma unroll
    for (int rnd = 0; rnd < 8; ++rnd) {
      float key; int idx;
      if (b0 >= b1) { key = b0; idx = lane; }
      else          { key = b1; idx = lane + 64; }
#pragma unroll
      for (int off = 1; off < 64; off <<= 1) {
        const float k2 = __shfl_xor(key, off);
        const int   i2 = __shfl_xor(idx, off);
        if (k2 > key || (k2 == key && i2 < idx)) { key = k2; idx = i2; }
      }
      const float cand = (idx < 64) ? s0 : s1;
      const float sw = __shfl(cand, idx & 63);
      ss = fmaf(sw, sw, ss);
      if (lane == rnd) { myv = sw; myi = idx; }
      if (lane == (idx & 63)) { if (idx < 64) b0 = -INFINITY; else b1 = -INFINITY; }
    }

    const float inv = 1.f / sqrtf(ss);
    if (lane < 8) {
      const size_t tok = tokBase + tk;
      outW[tok * 8 + lane] = myv * inv;
      outI[tok * 8 + lane] = (float)myi;
    }
  }
}

extern "C" void kernel_launch(void* const* d_in, const int* in_sizes, int n_in,
                              void* d_out, int out_size, void* d_ws, size_t ws_size,
                              hipStream_t stream) {
  const float* x    = (const float*)d_in[0];
  const float* w    = (const float*)d_in[1];
  const float* bias = (const float*)d_in[2];
  float* out = (float*)d_out;

  const int N = in_sizes[0] / DMODEL;  // 16384 tokens
  short* wp = (short*)d_ws;            // 64 chunks * 12288 shorts * 2 B = 1.5 MiB

  wprep<<<256, 256, 0, stream>>>(w, wp);
  router_fused<<<N / TOKT, 512, 0, stream>>>(x, wp, bias, out, out + (size_t)N * 8, N);
}

// Round 7
// 231.186 us; speedup vs baseline: 1.2660x; 1.1261x over previous
//
#include <hip/hip_runtime.h>
#include <math.h>

// MoE Router V8: x(16384,2048) fp32, W(128,2048) fp32, bias(128) fp32
// out = [weights(16384,8) fp32 | indices(16384,8) as fp32]
//
// R10: REVERT to the R3 two-kernel split-K structure (ledger analysis:
//  R3's kernels ran ~67us total vs 123-157us for every fused variant;
//  128x128 tiles + KS=4 give 96 MFMAs/staging-round fragment reuse that
//  256-small-block fused kernels structurally cannot).
//  Changes vs R3 (none affect values):
//   - wprep splits W once into 3 bf16 planes (identical split3 -> identical
//     values), stored per-chunk in the exact [3][128][32] LDS image.
//   - Kernel A stages W via 6x global_load_lds(16B) instead of per-block
//     fp32 loads + split3 + ds_write: staging VALU ~halves (m80: staging
//     was VALU-bound), W fetch becomes bf16 from L2-warm wp.
//  x staging, fragment reads, 6-MFMA chain, epilogue, and router_topk are
//  VERBATIM R3 -> bit-identical output to the passing R3/R6.

#define NE     128
#define TOKT   128   // tokens per tile (kernel A)
#define KC     32    // k per chunk (one 16x16x32 MFMA step)
#define KS     4     // split-K
#define DMODEL 2048
#define DSLICE (DMODEL / KS)          // 512
#define CHUNK_SH (3 * NE * KC)        // 12288 shorts per chunk image

typedef __attribute__((ext_vector_type(8))) short short8;
typedef __attribute__((ext_vector_type(4))) short s16x4;
typedef __attribute__((ext_vector_type(4))) float f32x4;

union S8  { short s[8]; short8 v; };
union S4u { short s[4]; s16x4 v; };

// split one fp32 into 3 truncated bf16 planes (exact residuals), slot j of 8
__device__ __forceinline__ void split3(float f, S8& hi, S8& mi, S8& lo, int j) {
  const unsigned u0 = __float_as_uint(f);
  const float hif = __uint_as_float(u0 & 0xFFFF0000u);
  const float r1 = f - hif;                      // exact
  const unsigned u1 = __float_as_uint(r1);
  const float mif = __uint_as_float(u1 & 0xFFFF0000u);
  const float r2 = r1 - mif;                     // exact
  hi.s[j] = (short)(u0 >> 16);
  mi.s[j] = (short)(u1 >> 16);
  lo.s[j] = (short)(__float_as_uint(r2) >> 16);
}

// 4-slot variant for wprep (same arithmetic -> same bf16 values as R3's
// in-kernel W split)
__device__ __forceinline__ void split3w(float f, S4u& hi, S4u& mi, S4u& lo, int j) {
  const unsigned u0 = __float_as_uint(f);
  const float hif = __uint_as_float(u0 & 0xFFFF0000u);
  const float r1 = f - hif;
  const unsigned u1 = __float_as_uint(r1);
  const float mif = __uint_as_float(u1 & 0xFFFF0000u);
  const float r2 = r1 - mif;
  hi.s[j] = (short)(u0 >> 16);
  mi.s[j] = (short)(u1 >> 16);
  lo.s[j] = (short)(__float_as_uint(r2) >> 16);
}

// W planes precompute: wp[chunk][p][e][kk]
__global__ __launch_bounds__(256) void wprep(const float* __restrict__ w,
                                             short* __restrict__ wp) {
  const int gid = blockIdx.x * 256 + threadIdx.x;  // 65536 threads
  const int e = gid >> 9;                          // expert 0..127
  const int g = gid & 511;                         // float4 group in row
  const int k = g << 2;
  const int chunk = k >> 5;
  const int kk = k & 31;
  const f32x4 a = *(const f32x4*)(w + (size_t)e * DMODEL + k);
  S4u hi, mi, lo;
  split3w(a[0], hi, mi, lo, 0); split3w(a[1], hi, mi, lo, 1);
  split3w(a[2], hi, mi, lo, 2); split3w(a[3], hi, mi, lo, 3);
  short* base = wp + (size_t)chunk * CHUNK_SH + (size_t)e * KC + kk;
  *(s16x4*)(base)               = hi.v;
  *(s16x4*)(base + NE * KC)     = mi.v;
  *(s16x4*)(base + 2 * NE * KC) = lo.v;
}

__device__ __forceinline__ void gll16(const short* g, short* l) {
  __builtin_amdgcn_global_load_lds(
      (const __attribute__((address_space(1))) void*)g,
      (__attribute__((address_space(3))) void*)l, 16, 0, 0);
}

__global__ __launch_bounds__(256) void logits_mfma(
    const float* __restrict__ x, const short* __restrict__ wp,
    float* __restrict__ part, int N) {
  // [plane][row][k]: row stride 32 bf16 = 64 B; frag reads cover a
  // contiguous 1 KiB per wave -> conflict-free b128. (verbatim R3 layout)
  __shared__ short xs[3][TOKT][KC];
  __shared__ __align__(16) short wsm[3][NE][KC];

  const int tid  = threadIdx.x;
  const int wave = tid >> 6;
  const int lane = tid & 63;
  const int wm = wave >> 1;        // wave-grid 2x2: m half
  const int wn = wave & 1;         // n half
  const int quad = lane >> 4;
  const int l16  = lane & 15;
  const size_t tokBase = (size_t)blockIdx.x * TOKT;
  const int d0 = blockIdx.y * DSLICE;

  // x staging assignment: 2 threads per row, 16 consecutive k each
  const int r = tid >> 1;          // row 0..127 (token row)
  const int h = tid & 1;           // k half (0 or 16)

  f32x4 acc[4][4];
#pragma unroll
  for (int i = 0; i < 4; ++i)
#pragma unroll
    for (int j = 0; j < 4; ++j) acc[i][j] = (f32x4)(0.f);

  for (int kc = 0; kc < DSLICE; kc += KC) {
    __syncthreads();
    // ---- stage x: fp32 -> 3 bf16 planes, two 8-k runs per thread (R3) ----
    {
      const float* gx = x + (tokBase + r) * DMODEL + d0 + kc + h * 16;
#pragma unroll
      for (int run = 0; run < 2; ++run) {
        const float4 a0 = *(const float4*)(gx + run * 8);
        const float4 a1 = *(const float4*)(gx + run * 8 + 4);
        S8 hi, mi, lo;
        split3(a0.x, hi, mi, lo, 0); split3(a0.y, hi, mi, lo, 1);
        split3(a0.z, hi, mi, lo, 2); split3(a0.w, hi, mi, lo, 3);
        split3(a1.x, hi, mi, lo, 4); split3(a1.y, hi, mi, lo, 5);
        split3(a1.z, hi, mi, lo, 6); split3(a1.w, hi, mi, lo, 7);
        const int kk = h * 16 + run * 8;
        *(short8*)&xs[0][r][kk] = hi.v;
        *(short8*)&xs[1][r][kk] = mi.v;
        *(short8*)&xs[2][r][kk] = lo.v;
      }
    }
    // ---- stage W: 6x global_load_lds 16B from precomputed chunk image ----
    {
      const int chunk = blockIdx.y * (DSLICE / KC) + (kc >> 5);
      const short* gsrc = wp + (size_t)chunk * CHUNK_SH + wave * 512 + lane * 8;
      short* ldst = &wsm[0][0][0] + wave * 512;   // wave-uniform dest
#pragma unroll
      for (int issue = 0; issue < 6; ++issue)
        gll16(gsrc + issue * 2048, ldst + issue * 2048);
    }
    __syncthreads();

    // ---- fragments + 6-plane MFMAs (verbatim R3) ----
    short8 af[4][3];
#pragma unroll
    for (int mt = 0; mt < 4; ++mt)
#pragma unroll
      for (int p = 0; p < 3; ++p)
        af[mt][p] = *(const short8*)&xs[p][wm * 64 + mt * 16 + l16][quad * 8];

#pragma unroll
    for (int nt = 0; nt < 4; ++nt) {
      short8 bf[3];
#pragma unroll
      for (int p = 0; p < 3; ++p)
        bf[p] = *(const short8*)&wsm[p][wn * 64 + nt * 16 + l16][quad * 8];
#pragma unroll
      for (int mt = 0; mt < 4; ++mt) {
        f32x4 c = acc[mt][nt];
        c = __builtin_amdgcn_mfma_f32_16x16x32_bf16(af[mt][0], bf[0], c, 0, 0, 0); // x1w1
        c = __builtin_amdgcn_mfma_f32_16x16x32_bf16(af[mt][0], bf[1], c, 0, 0, 0); // x1w2
        c = __builtin_amdgcn_mfma_f32_16x16x32_bf16(af[mt][1], bf[0], c, 0, 0, 0); // x2w1
        c = __builtin_amdgcn_mfma_f32_16x16x32_bf16(af[mt][0], bf[2], c, 0, 0, 0); // x1w3
        c = __builtin_amdgcn_mfma_f32_16x16x32_bf16(af[mt][2], bf[0], c, 0, 0, 0); // x3w1
        c = __builtin_amdgcn_mfma_f32_16x16x32_bf16(af[mt][1], bf[1], c, 0, 0, 0); // x2w2
        acc[mt][nt] = c;
      }
    }
  }

  // ---- epilogue: partials[kb][tok][exp]; C/D: col=lane&15, row=quad*4+reg ----
#pragma unroll
  for (int mt = 0; mt < 4; ++mt)
#pragma unroll
    for (int nt = 0; nt < 4; ++nt) {
      const int ex = wn * 64 + nt * 16 + l16;
#pragma unroll
      for (int reg = 0; reg < 4; ++reg) {
        const size_t tok = tokBase + wm * 64 + mt * 16 + quad * 4 + reg;
        part[((size_t)blockIdx.y * N + tok) * NE + ex] = acc[mt][nt][reg];
      }
    }
}

// One wave (64 lanes) per token; lane owns experts {lane, lane+64}. (verbatim R3)
__global__ __launch_bounds__(256) void router_topk(
    const float* __restrict__ part, const float* __restrict__ bias,
    float* __restrict__ outW, float* __restrict__ outI, int ks, int N) {
  const int wave = threadIdx.x >> 6;
  const int lane = threadIdx.x & 63;
  const int token = blockIdx.x * 4 + wave;
  if (token >= N) return;

  float l0 = 0.f, l1 = 0.f;
  for (int k = 0; k < ks; ++k) {
    const float* p = part + ((size_t)k * N + token) * NE;
    l0 += p[lane];
    l1 += p[lane + 64];
  }

  float m = fmaxf(l0, l1);
#pragma unroll
  for (int off = 1; off < 64; off <<= 1) m = fmaxf(m, __shfl_xor(m, off));
  const float ev0 = __expf(l0 - m);
  const float ev1 = __expf(l1 - m);
  float zs = ev0 + ev1;
#pragma unroll
  for (int off = 1; off < 64; off <<= 1) zs += __shfl_xor(zs, off);
  const float s0 = ev0 / zs;
  const float s1 = ev1 / zs;

  float b0 = s0 + bias[lane];
  float b1 = s1 + bias[lane + 64];

  float myv = 0.f;
  int myi = 0;
  float ss = 0.f;
#pragma unroll
  for (int rnd = 0; rnd < 8; ++rnd) {
    float key; int idx;
    if (b0 >= b1) { key = b0; idx = lane; }
    else          { key = b1; idx = lane + 64; }
#pragma unroll
    for (int off = 1; off < 64; off <<= 1) {
      const float k2 = __shfl_xor(key, off);
      const int   i2 = __shfl_xor(idx, off);
      if (k2 > key || (k2 == key && i2 < idx)) { key = k2; idx = i2; }
    }
    const float cand = (idx < 64) ? s0 : s1;
    const float sw = __shfl(cand, idx & 63);
    ss = fmaf(sw, sw, ss);
    if (lane == rnd) { myv = sw; myi = idx; }
    if (lane == (idx & 63)) { if (idx < 64) b0 = -INFINITY; else b1 = -INFINITY; }
  }

  const float inv = 1.f / sqrtf(ss);
  if (lane < 8) {
    outW[(size_t)token * 8 + lane] = myv * inv;
    outI[(size_t)token * 8 + lane] = (float)myi;
  }
}

extern "C" void kernel_launch(void* const* d_in, const int* in_sizes, int n_in,
                              void* d_out, int out_size, void* d_ws, size_t ws_size,
                              hipStream_t stream) {
  const float* x    = (const float*)d_in[0];
  const float* w    = (const float*)d_in[1];
  const float* bias = (const float*)d_in[2];
  float* out = (float*)d_out;

  const int N = in_sizes[0] / DMODEL;        // 16384 tokens
  short* wp  = (short*)d_ws;                 // 1.5 MiB of W planes
  float* part = (float*)((char*)d_ws + (4 << 20));  // KS*N*128*4 B = 33.5 MB

  wprep<<<256, 256, 0, stream>>>(w, wp);
  logits_mfma<<<dim3(N / TOKT, KS), 256, 0, stream>>>(x, wp, part, N);
  router_topk<<<(N + 3) / 4, 256, 0, stream>>>(part, bias, out, out + (size_t)N * 8, KS, N);
}

// Round 8
// 231.074 us; speedup vs baseline: 1.2666x; 1.0005x over previous
//
#include <hip/hip_runtime.h>
#include <math.h>

// MoE Router V9: x(16384,2048) fp32, W(128,2048) fp32, bias(128) fp32
// out = [weights(16384,8) fp32 | indices(16384,8) as fp32]
//
// R11: R3/R10 two-kernel structure + counted-vmcnt pipelined K-loop (T3/T4).
//  R10 post-mortem: gll alone didn't help because __syncthreads drains
//  vmcnt(0) every chunk -> x HBM latency exposed 16x/block. Now:
//   - x prefetched 2 chunks ahead in regs (same values/slots -> same split3
//     bits as R3's staging);
//   - W double-buffered in LDS via 6x global_load_lds, staged 1 chunk ahead;
//   - raw s_barrier + counted s_waitcnt vmcnt(10)/[tail 6,0] + lgkmcnt(0);
//     prefetch loads stay in flight across barriers (never drain mid-loop);
//   - sched_barrier(0) after each barrier (rule #18).
//  Arithmetic (fragment values, 6-MFMA chain order, chunk order, epilogue,
//  topk summation) verbatim R3 -> bit-identical output to passing R3/R6/R10.

#define NE     128
#define TOKT   128   // tokens per tile (kernel A)
#define KC     32    // k per chunk (one 16x16x32 MFMA step)
#define KS     4     // split-K
#define DMODEL 2048
#define DSLICE (DMODEL / KS)          // 512
#define NCH    (DSLICE / KC)          // 16 chunks per block
#define CHUNK_SH (3 * NE * KC)        // 12288 shorts per chunk image

typedef __attribute__((ext_vector_type(8))) short short8;
typedef __attribute__((ext_vector_type(4))) short s16x4;
typedef __attribute__((ext_vector_type(4))) float f32x4;

union S8  { short s[8]; short8 v; };
union S4u { short s[4]; s16x4 v; };

// split one fp32 into 3 truncated bf16 planes (exact residuals), slot j of 8
__device__ __forceinline__ void split3(float f, S8& hi, S8& mi, S8& lo, int j) {
  const unsigned u0 = __float_as_uint(f);
  const float hif = __uint_as_float(u0 & 0xFFFF0000u);
  const float r1 = f - hif;                      // exact
  const unsigned u1 = __float_as_uint(r1);
  const float mif = __uint_as_float(u1 & 0xFFFF0000u);
  const float r2 = r1 - mif;                     // exact
  hi.s[j] = (short)(u0 >> 16);
  mi.s[j] = (short)(u1 >> 16);
  lo.s[j] = (short)(__float_as_uint(r2) >> 16);
}

// 4-slot variant for wprep (same arithmetic -> same bf16 values)
__device__ __forceinline__ void split3w(float f, S4u& hi, S4u& mi, S4u& lo, int j) {
  const unsigned u0 = __float_as_uint(f);
  const float hif = __uint_as_float(u0 & 0xFFFF0000u);
  const float r1 = f - hif;
  const unsigned u1 = __float_as_uint(r1);
  const float mif = __uint_as_float(u1 & 0xFFFF0000u);
  const float r2 = r1 - mif;
  hi.s[j] = (short)(u0 >> 16);
  mi.s[j] = (short)(u1 >> 16);
  lo.s[j] = (short)(__float_as_uint(r2) >> 16);
}

// W planes precompute: wp[chunk][p][e][kk]
__global__ __launch_bounds__(256) void wprep(const float* __restrict__ w,
                                             short* __restrict__ wp) {
  const int gid = blockIdx.x * 256 + threadIdx.x;  // 65536 threads
  const int e = gid >> 9;                          // expert 0..127
  const int g = gid & 511;                         // float4 group in row
  const int k = g << 2;
  const int chunk = k >> 5;
  const int kk = k & 31;
  const f32x4 a = *(const f32x4*)(w + (size_t)e * DMODEL + k);
  S4u hi, mi, lo;
  split3w(a[0], hi, mi, lo, 0); split3w(a[1], hi, mi, lo, 1);
  split3w(a[2], hi, mi, lo, 2); split3w(a[3], hi, mi, lo, 3);
  short* base = wp + (size_t)chunk * CHUNK_SH + (size_t)e * KC + kk;
  *(s16x4*)(base)               = hi.v;
  *(s16x4*)(base + NE * KC)     = mi.v;
  *(s16x4*)(base + 2 * NE * KC) = lo.v;
}

__device__ __forceinline__ void gll16(const short* g, short* l) {
  __builtin_amdgcn_global_load_lds(
      (const __attribute__((address_space(1))) void*)g,
      (__attribute__((address_space(3))) void*)l, 16, 0, 0);
}

__global__ __launch_bounds__(256) void logits_mfma(
    const float* __restrict__ x, const short* __restrict__ wp,
    float* __restrict__ part, int N) {
  // xs single-buffered (R3 layout: conflict-free 1 KiB frag reads);
  // wsm double-buffered for the gll pipeline. 24 + 48 KB = 73.7 KB LDS.
  __shared__ short xs[3][TOKT][KC];
  __shared__ __align__(16) short wsm[2][3][NE][KC];

  const int tid  = threadIdx.x;
  const int wave = tid >> 6;
  const int lane = tid & 63;
  const int wm = wave >> 1;        // wave-grid 2x2: m half
  const int wn = wave & 1;         // n half
  const int quad = lane >> 4;
  const int l16  = lane & 15;
  const size_t tokBase = (size_t)blockIdx.x * TOKT;
  const int d0 = blockIdx.y * DSLICE;
  const int chunkBase = blockIdx.y * NCH;

  // x staging assignment: 2 threads per row, 16 consecutive k each
  const int r = tid >> 1;          // row 0..127 (token row)
  const int h = tid & 1;           // k half (0 or 16)
  const float* gx = x + (tokBase + r) * DMODEL + d0 + h * 16;

  f32x4 acc[4][4];
#pragma unroll
  for (int i = 0; i < 4; ++i)
#pragma unroll
    for (int j = 0; j < 4; ++j) acc[i][j] = (f32x4)(0.f);

  // ---- helpers (buf literal at call sites) ----
  auto stage_w = [&](int buf, int c) {     // 6x gll16: chunk c -> wsm[buf]
    const short* gsrc = wp + (size_t)(chunkBase + c) * CHUNK_SH + wave * 512 + lane * 8;
    short* ldst = &wsm[buf][0][0][0] + wave * 512;   // wave-uniform dest
#pragma unroll
    for (int i = 0; i < 6; ++i)
      gll16(gsrc + i * 2048, ldst + i * 2048);
  };
  auto load_x = [&](float4 (&xr)[4], int t) {
    const float* g = gx + t * KC;
    xr[0] = *(const float4*)(g);
    xr[1] = *(const float4*)(g + 4);
    xr[2] = *(const float4*)(g + 8);
    xr[3] = *(const float4*)(g + 12);
  };
  auto stage_x = [&](const float4 (&xr)[4]) {  // identical slots/values to R3
#pragma unroll
    for (int run = 0; run < 2; ++run) {
      const float4 a0 = xr[2 * run];
      const float4 a1 = xr[2 * run + 1];
      S8 hi, mi, lo;
      split3(a0.x, hi, mi, lo, 0); split3(a0.y, hi, mi, lo, 1);
      split3(a0.z, hi, mi, lo, 2); split3(a0.w, hi, mi, lo, 3);
      split3(a1.x, hi, mi, lo, 4); split3(a1.y, hi, mi, lo, 5);
      split3(a1.z, hi, mi, lo, 6); split3(a1.w, hi, mi, lo, 7);
      const int kk = h * 16 + run * 8;
      *(short8*)&xs[0][r][kk] = hi.v;
      *(short8*)&xs[1][r][kk] = mi.v;
      *(short8*)&xs[2][r][kk] = lo.v;
    }
  };
  auto compute = [&](int buf) {            // verbatim R3 fragments + MFMAs
    short8 af[4][3];
#pragma unroll
    for (int mt = 0; mt < 4; ++mt)
#pragma unroll
      for (int p = 0; p < 3; ++p)
        af[mt][p] = *(const short8*)&xs[p][wm * 64 + mt * 16 + l16][quad * 8];
#pragma unroll
    for (int nt = 0; nt < 4; ++nt) {
      short8 bf[3];
#pragma unroll
      for (int p = 0; p < 3; ++p)
        bf[p] = *(const short8*)&wsm[buf][p][wn * 64 + nt * 16 + l16][quad * 8];
#pragma unroll
      for (int mt = 0; mt < 4; ++mt) {
        f32x4 c = acc[mt][nt];
        c = __builtin_amdgcn_mfma_f32_16x16x32_bf16(af[mt][0], bf[0], c, 0, 0, 0); // x1w1
        c = __builtin_amdgcn_mfma_f32_16x16x32_bf16(af[mt][0], bf[1], c, 0, 0, 0); // x1w2
        c = __builtin_amdgcn_mfma_f32_16x16x32_bf16(af[mt][1], bf[0], c, 0, 0, 0); // x2w1
        c = __builtin_amdgcn_mfma_f32_16x16x32_bf16(af[mt][0], bf[2], c, 0, 0, 0); // x1w3
        c = __builtin_amdgcn_mfma_f32_16x16x32_bf16(af[mt][2], bf[0], c, 0, 0, 0); // x3w1
        c = __builtin_amdgcn_mfma_f32_16x16x32_bf16(af[mt][1], bf[1], c, 0, 0, 0); // x2w2
        acc[mt][nt] = c;
      }
    }
  };

  // ---- prologue: W(0) in flight; x(0),x(1) in regs ----
  float4 xA[4], xB[4];
  stage_w(0, 0);
  load_x(xA, 0);
  load_x(xB, 1);

  // ---- main loop: chunks 0..13 as 7 even/odd pairs, counted vmcnt(10) ----
#pragma unroll 1
  for (int t = 0; t < NCH - 2; t += 2) {
    // even body: consume x(t)=xA, compute chunk t from wsm[0]
    stage_x(xA);                 // split3 + ds_write (compiler waits xA regs)
    stage_w(1, t + 1);           // gll W(t+1) -> wsm[1]
    load_x(xA, t + 2);           // prefetch x(t+2)
    // younger in flight: 6 gll(t+1) + 4 x(t+2) = 10 -> W(t) & x(t+1) retired
    asm volatile("s_waitcnt vmcnt(10) lgkmcnt(0)" ::: "memory");
    __builtin_amdgcn_s_barrier();
    __builtin_amdgcn_sched_barrier(0);
    compute(0);
    __builtin_amdgcn_s_barrier();          // xs safe to rewrite
    __builtin_amdgcn_sched_barrier(0);
    // odd body: consume x(t+1)=xB, compute chunk t+1 from wsm[1]
    stage_x(xB);
    stage_w(0, t + 2);           // gll W(t+2) -> wsm[0]
    load_x(xB, t + 3);           // prefetch x(t+3)
    asm volatile("s_waitcnt vmcnt(10) lgkmcnt(0)" ::: "memory");
    __builtin_amdgcn_s_barrier();
    __builtin_amdgcn_sched_barrier(0);
    compute(1);
    __builtin_amdgcn_s_barrier();
    __builtin_amdgcn_sched_barrier(0);
  }
  // ---- peeled tail: chunk 14 (vmcnt(6)), chunk 15 (vmcnt(0)) ----
  stage_x(xA);                   // x(14)
  stage_w(1, NCH - 1);           // gll W(15) -> wsm[1]
  asm volatile("s_waitcnt vmcnt(6) lgkmcnt(0)" ::: "memory");
  __builtin_amdgcn_s_barrier();
  __builtin_amdgcn_sched_barrier(0);
  compute(0);                    // W(14) from wsm[0]
  __builtin_amdgcn_s_barrier();
  __builtin_amdgcn_sched_barrier(0);
  stage_x(xB);                   // x(15)
  asm volatile("s_waitcnt vmcnt(0) lgkmcnt(0)" ::: "memory");
  __builtin_amdgcn_s_barrier();
  __builtin_amdgcn_sched_barrier(0);
  compute(1);                    // W(15) from wsm[1]

  // ---- epilogue: partials[kb][tok][exp]; C/D: col=lane&15, row=quad*4+reg ----
#pragma unroll
  for (int mt = 0; mt < 4; ++mt)
#pragma unroll
    for (int nt = 0; nt < 4; ++nt) {
      const int ex = wn * 64 + nt * 16 + l16;
#pragma unroll
      for (int reg = 0; reg < 4; ++reg) {
        const size_t tok = tokBase + wm * 64 + mt * 16 + quad * 4 + reg;
        part[((size_t)blockIdx.y * N + tok) * NE + ex] = acc[mt][nt][reg];
      }
    }
}

// One wave (64 lanes) per token; lane owns experts {lane, lane+64}. (verbatim R3)
__global__ __launch_bounds__(256) void router_topk(
    const float* __restrict__ part, const float* __restrict__ bias,
    float* __restrict__ outW, float* __restrict__ outI, int ks, int N) {
  const int wave = threadIdx.x >> 6;
  const int lane = threadIdx.x & 63;
  const int token = blockIdx.x * 4 + wave;
  if (token >= N) return;

  float l0 = 0.f, l1 = 0.f;
  for (int k = 0; k < ks; ++k) {
    const float* p = part + ((size_t)k * N + token) * NE;
    l0 += p[lane];
    l1 += p[lane + 64];
  }

  float m = fmaxf(l0, l1);
#pragma unroll
  for (int off = 1; off < 64; off <<= 1) m = fmaxf(m, __shfl_xor(m, off));
  const float ev0 = __expf(l0 - m);
  const float ev1 = __expf(l1 - m);
  float zs = ev0 + ev1;
#pragma unroll
  for (int off = 1; off < 64; off <<= 1) zs += __shfl_xor(zs, off);
  const float s0 = ev0 / zs;
  const float s1 = ev1 / zs;

  float b0 = s0 + bias[lane];
  float b1 = s1 + bias[lane + 64];

  float myv = 0.f;
  int myi = 0;
  float ss = 0.f;
#pragma unroll
  for (int rnd = 0; rnd < 8; ++rnd) {
    float key; int idx;
    if (b0 >= b1) { key = b0; idx = lane; }
    else          { key = b1; idx = lane + 64; }
#pragma unroll
    for (int off = 1; off < 64; off <<= 1) {
      const float k2 = __shfl_xor(key, off);
      const int   i2 = __shfl_xor(idx, off);
      if (k2 > key || (k2 == key && i2 < idx)) { key = k2; idx = i2; }
    }
    const float cand = (idx < 64) ? s0 : s1;
    const float sw = __shfl(cand, idx & 63);
    ss = fmaf(sw, sw, ss);
    if (lane == rnd) { myv = sw; myi = idx; }
    if (lane == (idx & 63)) { if (idx < 64) b0 = -INFINITY; else b1 = -INFINITY; }
  }

  const float inv = 1.f / sqrtf(ss);
  if (lane < 8) {
    outW[(size_t)token * 8 + lane] = myv * inv;
    outI[(size_t)token * 8 + lane] = (float)myi;
  }
}

extern "C" void kernel_launch(void* const* d_in, const int* in_sizes, int n_in,
                              void* d_out, int out_size, void* d_ws, size_t ws_size,
                              hipStream_t stream) {
  const float* x    = (const float*)d_in[0];
  const float* w    = (const float*)d_in[1];
  const float* bias = (const float*)d_in[2];
  float* out = (float*)d_out;

  const int N = in_sizes[0] / DMODEL;        // 16384 tokens
  short* wp  = (short*)d_ws;                 // 1.5 MiB of W planes
  float* part = (float*)((char*)d_ws + (4 << 20));  // KS*N*128*4 B = 33.5 MB

  wprep<<<256, 256, 0, stream>>>(w, wp);
  logits_mfma<<<dim3(N / TOKT, KS), 256, 0, stream>>>(x, wp, part, N);
  router_topk<<<(N + 3) / 4, 256, 0, stream>>>(part, bias, out, out + (size_t)N * 8, KS, N);
}